// Round 7
// baseline (935.989 us; speedup 1.0000x reference)
//
#include <hip/hip_runtime.h>

// TT-chain: N=65536, L=128, D=4, R=8, O=2.
//   m = x[n,0] @ core_first[0]
//   for c in 0..125: m[l] = sum_{k,j} m[k]*cm[c,k,j,l]*x[n,c+1,j]
//   out[n,:] = sum_{k,j} m[k]*cl[k,j,:]*x[n,127,j]
// cm[:, :, 3, :] == I -> j=3 term is x.w*m[l]. Full fp32 (exact).
//
// R12 design: R11's quad-split (4 lanes/sample, cores as per-lane data,
// m gathered by dpp quad_perm, v_pk_fma_f32 pairs, 4 waves/SIMD) with the
// software pipeline PINNED against compiler sinking.
//   R11 post-mortem: VGPR_Count=36 (vs ~110 needed for resident buffers)
//   proves the scheduler sank every prefetch load to its use site ->
//   ~5-6 serial L2 round-trips per step -> 1750 cyc/step, VALUBusy 11.6%.
//   R12 fixes: (1) FULL next-step slab (12 float4, k=0..7) prefetched one
//   step ahead into a double buffer (R11 loaded the k>=4 half in the same
//   step it was consumed -- exposed latency by construction); (2)
//   __builtin_amdgcn_sched_barrier(0) between the prefetch-issue block
//   and the compute block of every step -- loads can't sink, compute
//   can't hoist, and the buffers' live ranges span the fence so the
//   allocator must keep them in registers (~114 VGPR, fits the 128 cap
//   of launch_bounds(256,4)).
//
// Cycle model per wave-step: 13 VMEM issue + ~62 VALU (12 dpp + ~36
// pk/mul + misc) ~ 140 cyc; x4 waves/SIMD ~ 550 cyc/SIMD-step; 126 steps
// ~ 69k cyc ~ 29 us. HBM floor (x once) ~ 20 us. Target 30-45 us.

#define NTHREADS 256
#define SAMPLES_PER_BLOCK 64   // 4 waves x 16 quads

typedef float f2 __attribute__((ext_vector_type(2)));

#define QBCAST(k) ((k) | ((k) << 2) | ((k) << 4) | ((k) << 6))

template <int CTRL>
__device__ __forceinline__ float dppf(float v) {
    return __builtin_bit_cast(float,
        __builtin_amdgcn_mov_dpp(__builtin_bit_cast(int, v), CTRL, 0xf, 0xf, false));
}

// Pack cm[126,8,4,8] -> cpk[c][i][w], w = k*6 + j*2 + h, value
// cm[c,k,j,(i+4h)]: 48-dword slab per (c, lane-in-quad i).
// +192-dword zero pad (step-125 prefetch of "step 126").
__global__ __launch_bounds__(NTHREADS) void pack_cores_q(
    const float* __restrict__ cm, float* __restrict__ cpk)
{
    int t = blockIdx.x * NTHREADS + threadIdx.x;
    if (t >= 126 * 192 + 192) return;
    if (t >= 126 * 192) { cpk[t] = 0.f; return; }   // pad
    int c = t / 192, r = t % 192;
    int i = r / 48,  w = r % 48;
    int k = w / 6,   jj = w % 6;
    int j = jj >> 1, h = jj & 1;
    cpk[t] = cm[c * 256 + k * 32 + j * 8 + (i + 4 * h)];
}

// pair (l=i, l=i+4) for (k,j) from a 12-float4 slab: dwords k*6+j*2, +1
// (always an aligned .xy or .zw pair since k*6+j*2 is even)
#define PF2(S, K, J) ((((K)*6 + (J)*2) & 2) \
    ? f2{S[((K)*6 + (J)*2) >> 2].z, S[((K)*6 + (J)*2) >> 2].w} \
    : f2{S[((K)*6 + (J)*2) >> 2].x, S[((K)*6 + (J)*2) >> 2].y})

#define KB(MS, S, K) {                                           \
    const float mk = dppf<QBCAST((K) & 3)>(MS);                  \
    f2 t = PF2(S, K, 0) * xx;                                    \
    t = PF2(S, K, 1) * xy + t;                                   \
    t = PF2(S, K, 2) * xz + t;                                   \
    nm = f2{mk, mk} * t + nm; }

#define STEPQ(S)  {                                              \
    const float x0 = dppf<QBCAST(0)>(xc);                        \
    const float x1 = dppf<QBCAST(1)>(xc);                        \
    const float x2 = dppf<QBCAST(2)>(xc);                        \
    const float x3 = dppf<QBCAST(3)>(xc);                        \
    const f2 xx = {x0, x0}, xy = {x1, x1}, xz = {x2, x2};        \
    f2 nm = f2{x3, x3} * m2;                                     \
    KB(m2.x, S, 0) KB(m2.x, S, 1) KB(m2.x, S, 2) KB(m2.x, S, 3)  \
    KB(m2.y, S, 4) KB(m2.y, S, 5) KB(m2.y, S, 6) KB(m2.y, S, 7)  \
    m2 = nm; }

__global__ __launch_bounds__(NTHREADS, 4) void tt_chain_p(
    const float* __restrict__ x,          // [N,128,4]
    const float* __restrict__ cpk,        // packed cores (+192-dword pad)
    const float* __restrict__ cf,         // [1,4,8]
    const float* __restrict__ cl,         // [8,4,2]
    float* __restrict__ out)              // [N,2]
{
    const int tid = threadIdx.x;
    const int i   = tid & 3;                                   // lane-in-quad
    const int n   = blockIdx.x * SAMPLES_PER_BLOCK + (tid >> 2);

    const float* __restrict__ xF = x + (size_t)n * 512;        // dwords
    const float4* __restrict__ cpk4 =
        reinterpret_cast<const float4*>(cpk) + i * 12;         // lane's slabs

    // ---- prologue ----
    float4 B0[12], B1[12];
    #pragma unroll
    for (int q = 0; q < 12; ++q) B0[q] = cpk4[q];              // step 0 slab

    // x component pipeline (lane's component i): rows 1,2,3
    float xc  = xF[4 + i];
    float xn1 = xF[8 + i];
    float xn2 = xF[12 + i];

    // m init from row 0: m[l] = sum_j x0_j * cf[j*8+l], l = i and i+4
    const float4 xr0 = reinterpret_cast<const float4*>(xF)[0];
    f2 m2;
    m2.x = fmaf(cf[i],      xr0.x, fmaf(cf[8 + i],  xr0.y,
           fmaf(cf[16 + i], xr0.z, cf[24 + i] * xr0.w)));
    m2.y = fmaf(cf[4 + i],  xr0.x, fmaf(cf[12 + i], xr0.y,
           fmaf(cf[20 + i], xr0.z, cf[28 + i] * xr0.w)));

    // ---- 63 double-steps: c = 0..125 ----
    #pragma unroll 1
    for (int t = 0; t < 63; ++t) {
        const int c0 = 2 * t;
        {   // step c0: issue slab c0+1 -> B1, x row c0+4; fence; compute B0
            #pragma unroll
            for (int q = 0; q < 12; ++q) B1[q] = cpk4[(c0 + 1) * 48 + q];
            const int tx = (c0 + 4 < 128) ? (c0 + 4) * 4 : 508;
            const float xload = xF[tx + i];
            __builtin_amdgcn_sched_barrier(0);   // pin loads above compute
            STEPQ(B0)
            xc = xn1; xn1 = xn2; xn2 = xload;
        }
        {   // step c0+1: issue slab c0+2 -> B0 (c=126 hits pad); compute B1
            #pragma unroll
            for (int q = 0; q < 12; ++q) B0[q] = cpk4[(c0 + 2) * 48 + q];
            const int tx = (c0 + 5 < 128) ? (c0 + 5) * 4 : 508;
            const float xload = xF[tx + i];
            __builtin_amdgcn_sched_barrier(0);
            STEPQ(B1)
            xc = xn1; xn1 = xn2; xn2 = xload;
        }
    }

    // ---- epilogue: xc now = row 127 component i ----
    {
        const float e0 = dppf<QBCAST(0)>(xc);
        const float e1 = dppf<QBCAST(1)>(xc);
        const float e2 = dppf<QBCAST(2)>(xc);
        const float e3 = dppf<QBCAST(3)>(xc);
        const float xj[4] = { e0, e1, e2, e3 };
        // lane's partial over its two k's (k=i and k=i+4)
        float o0 = 0.f, o1 = 0.f;
        #pragma unroll
        for (int j = 0; j < 4; ++j) {
            o0 += xj[j] * (m2.x * cl[i * 8 + j * 2 + 0] +
                           m2.y * cl[(i + 4) * 8 + j * 2 + 0]);
            o1 += xj[j] * (m2.x * cl[i * 8 + j * 2 + 1] +
                           m2.y * cl[(i + 4) * 8 + j * 2 + 1]);
        }
        // quad reduction (sum over the 4 lanes of the sample)
        o0 += dppf<0xB1>(o0);   // quad_perm(1,0,3,2)
        o0 += dppf<0x4E>(o0);   // quad_perm(2,3,0,1)
        o1 += dppf<0xB1>(o1);
        o1 += dppf<0x4E>(o1);
        if (i == 0)
            reinterpret_cast<float2*>(out)[n] = make_float2(o0, o1);
    }
}

extern "C" void kernel_launch(void* const* d_in, const int* in_sizes, int n_in,
                              void* d_out, int out_size, void* d_ws, size_t ws_size,
                              hipStream_t stream) {
    const float* x  = (const float*)d_in[0];   // [N,128,4]
    const float* cf = (const float*)d_in[1];   // [1,4,8]
    const float* cm = (const float*)d_in[2];   // [126,8,4,8]
    const float* cl = (const float*)d_in[3];   // [8,4,2]
    float* out = (float*)d_out;                // [N,2]

    const int N = in_sizes[0] / (128 * 4);

    // packed fp32 cores: (126*192 + 192) dwords = 97536 B in workspace
    float* cpk = (float*)d_ws;

    pack_cores_q<<<(126 * 192 + 192 + NTHREADS - 1) / NTHREADS, NTHREADS, 0, stream>>>(cm, cpk);

    tt_chain_p<<<N / SAMPLES_PER_BLOCK, NTHREADS, 0, stream>>>(x, cpk, cf, cl, out);
}

// Round 8
// 495.558 us; speedup vs baseline: 1.8888x; 1.8888x over previous
//
#include <hip/hip_runtime.h>

// TT-chain: N=65536, L=128, D=4, R=8, O=2.
//   m = x[n,0] @ core_first[0]
//   for c in 0..125: m[l] = sum_{k,j} m[k]*cm[c,k,j,l]*x[n,c+1,j]
//   out[n,:] = sum_{k,j} m[k]*cl[k,j,:]*x[n,127,j]
// cm[:, :, 3, :] == I -> j=3 term is x.w*m[l]. Full fp32 (exact).
//
// R13 design: R12 (quad-split + full-slab double buffer + sched_barrier
// pipeline pinning) with __launch_bounds__(256, 2): 256-VGPR cap.
//   R11 post-mortem: no fence -> compiler SANK all prefetch loads to
//     their uses (VGPR=36), ~6 serial L2 round-trips/step -> 368 us.
//   R12 post-mortem: fence worked, but launch_bounds(256,4) caps waves
//     at 128 VGPRs < ~130 needed -> allocator SPILLED the core buffers
//     to scratch: WRITE_SIZE 512KB -> 1.24 GB, FETCH 66 -> 351 MB,
//     VGPR=64, VALUBusy 5% -> 808 us. Same constraint, violated from
//     the other side.
//   R13: cap 256 VGPRs (2 waves/SIMD). Pinned buffers (~130 regs) fit
//   with slack -> no sink (fence) and no spill (budget). Latency is
//   hidden explicitly by the 1-step prefetch distance (~300 cyc between
//   issue and first use at 2 waves/SIMD), not by TLP.
//
// Cycle model per wave-step: 13 VMEM + ~62 VALU ~ 150 cyc; 2 waves/SIMD
// -> ~300 cyc per SIMD-step (32 samples); 126 steps x 2 passes ~ 75k cyc
// ~ 31 us. HBM floor (x once) ~ 20 us. Verification signals: WRITE_SIZE
// back to ~512 KB, VGPR ~120-180.

#define NTHREADS 256
#define SAMPLES_PER_BLOCK 64   // 4 waves x 16 quads

typedef float f2 __attribute__((ext_vector_type(2)));

#define QBCAST(k) ((k) | ((k) << 2) | ((k) << 4) | ((k) << 6))

template <int CTRL>
__device__ __forceinline__ float dppf(float v) {
    return __builtin_bit_cast(float,
        __builtin_amdgcn_mov_dpp(__builtin_bit_cast(int, v), CTRL, 0xf, 0xf, false));
}

// Pack cm[126,8,4,8] -> cpk[c][i][w], w = k*6 + j*2 + h, value
// cm[c,k,j,(i+4h)]: 48-dword slab per (c, lane-in-quad i).
// +192-dword zero pad (step-125 prefetch of "step 126").
__global__ __launch_bounds__(NTHREADS) void pack_cores_q(
    const float* __restrict__ cm, float* __restrict__ cpk)
{
    int t = blockIdx.x * NTHREADS + threadIdx.x;
    if (t >= 126 * 192 + 192) return;
    if (t >= 126 * 192) { cpk[t] = 0.f; return; }   // pad
    int c = t / 192, r = t % 192;
    int i = r / 48,  w = r % 48;
    int k = w / 6,   jj = w % 6;
    int j = jj >> 1, h = jj & 1;
    cpk[t] = cm[c * 256 + k * 32 + j * 8 + (i + 4 * h)];
}

// pair (l=i, l=i+4) for (k,j) from a 12-float4 slab: dwords k*6+j*2, +1
// (always an aligned .xy or .zw pair since k*6+j*2 is even)
#define PF2(S, K, J) ((((K)*6 + (J)*2) & 2) \
    ? f2{S[((K)*6 + (J)*2) >> 2].z, S[((K)*6 + (J)*2) >> 2].w} \
    : f2{S[((K)*6 + (J)*2) >> 2].x, S[((K)*6 + (J)*2) >> 2].y})

#define KB(MS, S, K) {                                           \
    const float mk = dppf<QBCAST((K) & 3)>(MS);                  \
    f2 t = PF2(S, K, 0) * xx;                                    \
    t = PF2(S, K, 1) * xy + t;                                   \
    t = PF2(S, K, 2) * xz + t;                                   \
    nm = f2{mk, mk} * t + nm; }

#define STEPQ(S)  {                                              \
    const float x0 = dppf<QBCAST(0)>(xc);                        \
    const float x1 = dppf<QBCAST(1)>(xc);                        \
    const float x2 = dppf<QBCAST(2)>(xc);                        \
    const float x3 = dppf<QBCAST(3)>(xc);                        \
    const f2 xx = {x0, x0}, xy = {x1, x1}, xz = {x2, x2};        \
    f2 nm = f2{x3, x3} * m2;                                     \
    KB(m2.x, S, 0) KB(m2.x, S, 1) KB(m2.x, S, 2) KB(m2.x, S, 3)  \
    KB(m2.y, S, 4) KB(m2.y, S, 5) KB(m2.y, S, 6) KB(m2.y, S, 7)  \
    m2 = nm; }

__global__ __launch_bounds__(NTHREADS, 2) void tt_chain_p(
    const float* __restrict__ x,          // [N,128,4]
    const float* __restrict__ cpk,        // packed cores (+192-dword pad)
    const float* __restrict__ cf,         // [1,4,8]
    const float* __restrict__ cl,         // [8,4,2]
    float* __restrict__ out)              // [N,2]
{
    const int tid = threadIdx.x;
    const int i   = tid & 3;                                   // lane-in-quad
    const int n   = blockIdx.x * SAMPLES_PER_BLOCK + (tid >> 2);

    const float* __restrict__ xF = x + (size_t)n * 512;        // dwords
    const float4* __restrict__ cpk4 =
        reinterpret_cast<const float4*>(cpk) + i * 12;         // lane's slabs

    // ---- prologue ----
    float4 B0[12], B1[12];
    #pragma unroll
    for (int q = 0; q < 12; ++q) B0[q] = cpk4[q];              // step 0 slab

    // x component pipeline (lane's component i): rows 1,2,3
    float xc  = xF[4 + i];
    float xn1 = xF[8 + i];
    float xn2 = xF[12 + i];

    // m init from row 0: m[l] = sum_j x0_j * cf[j*8+l], l = i and i+4
    const float4 xr0 = reinterpret_cast<const float4*>(xF)[0];
    f2 m2;
    m2.x = fmaf(cf[i],      xr0.x, fmaf(cf[8 + i],  xr0.y,
           fmaf(cf[16 + i], xr0.z, cf[24 + i] * xr0.w)));
    m2.y = fmaf(cf[4 + i],  xr0.x, fmaf(cf[12 + i], xr0.y,
           fmaf(cf[20 + i], xr0.z, cf[28 + i] * xr0.w)));

    // ---- 63 double-steps: c = 0..125 ----
    #pragma unroll 1
    for (int t = 0; t < 63; ++t) {
        const int c0 = 2 * t;
        {   // step c0: issue slab c0+1 -> B1, x row c0+4; fence; compute B0
            #pragma unroll
            for (int q = 0; q < 12; ++q) B1[q] = cpk4[(c0 + 1) * 48 + q];
            const int tx = (c0 + 4 < 128) ? (c0 + 4) * 4 : 508;
            const float xload = xF[tx + i];
            __builtin_amdgcn_sched_barrier(0);   // pin loads above compute
            STEPQ(B0)
            xc = xn1; xn1 = xn2; xn2 = xload;
        }
        {   // step c0+1: issue slab c0+2 -> B0 (c=126 hits pad); compute B1
            #pragma unroll
            for (int q = 0; q < 12; ++q) B0[q] = cpk4[(c0 + 2) * 48 + q];
            const int tx = (c0 + 5 < 128) ? (c0 + 5) * 4 : 508;
            const float xload = xF[tx + i];
            __builtin_amdgcn_sched_barrier(0);
            STEPQ(B1)
            xc = xn1; xn1 = xn2; xn2 = xload;
        }
    }

    // ---- epilogue: xc now = row 127 component i ----
    {
        const float e0 = dppf<QBCAST(0)>(xc);
        const float e1 = dppf<QBCAST(1)>(xc);
        const float e2 = dppf<QBCAST(2)>(xc);
        const float e3 = dppf<QBCAST(3)>(xc);
        const float xj[4] = { e0, e1, e2, e3 };
        // lane's partial over its two k's (k=i and k=i+4)
        float o0 = 0.f, o1 = 0.f;
        #pragma unroll
        for (int j = 0; j < 4; ++j) {
            o0 += xj[j] * (m2.x * cl[i * 8 + j * 2 + 0] +
                           m2.y * cl[(i + 4) * 8 + j * 2 + 0]);
            o1 += xj[j] * (m2.x * cl[i * 8 + j * 2 + 1] +
                           m2.y * cl[(i + 4) * 8 + j * 2 + 1]);
        }
        // quad reduction (sum over the 4 lanes of the sample)
        o0 += dppf<0xB1>(o0);   // quad_perm(1,0,3,2)
        o0 += dppf<0x4E>(o0);   // quad_perm(2,3,0,1)
        o1 += dppf<0xB1>(o1);
        o1 += dppf<0x4E>(o1);
        if (i == 0)
            reinterpret_cast<float2*>(out)[n] = make_float2(o0, o1);
    }
}

extern "C" void kernel_launch(void* const* d_in, const int* in_sizes, int n_in,
                              void* d_out, int out_size, void* d_ws, size_t ws_size,
                              hipStream_t stream) {
    const float* x  = (const float*)d_in[0];   // [N,128,4]
    const float* cf = (const float*)d_in[1];   // [1,4,8]
    const float* cm = (const float*)d_in[2];   // [126,8,4,8]
    const float* cl = (const float*)d_in[3];   // [8,4,2]
    float* out = (float*)d_out;                // [N,2]

    const int N = in_sizes[0] / (128 * 4);

    // packed fp32 cores: (126*192 + 192) dwords = 97536 B in workspace
    float* cpk = (float*)d_ws;

    pack_cores_q<<<(126 * 192 + 192 + NTHREADS - 1) / NTHREADS, NTHREADS, 0, stream>>>(cm, cpk);

    tt_chain_p<<<N / SAMPLES_PER_BLOCK, NTHREADS, 0, stream>>>(x, cpk, cf, cl, out);
}

// Round 11
// 298.260 us; speedup vs baseline: 3.1382x; 1.6615x over previous
//
#include <hip/hip_runtime.h>

// TT-chain: N=65536, L=128, D=4, R=8, O=2.
//   m = x[n,0] @ core_first[0]
//   for c in 0..125: m[l] = sum_{k,j} m[k]*cm[c,k,j,l]*x[n,c+1,j]
//   out[n,:] = sum_{k,j} m[k]*cl[k,j,:]*x[n,127,j]
// cm[:, :, 3, :] == I -> j=3 term is x.w*m[l] (exact fp32 path).
//
// R16 design: quad-split (R11-R13's verified math) + per-wave private LDS
// rings staged via global_load_lds + fp16 cores (R5-proven numerics).
//   R14/R15 post-mortem: two NaN rounds from asm loads with REGISTER
//   destinations (async write to a reg the compiler believes defined).
//   global_load_lds eliminates the class: no reg dest (writes LDS), the
//   intrinsic is side-effecting (cannot sink -- R11's failure), and with
//   x ALSO staged through LDS there are ZERO compiler VMEM ops in the
//   loop -> counted WAITVM(4) is deterministic (R13/R15's count-mixing
//   failure gone). Per-wave private rings -> no barriers, no cross-wave
//   races. fp16 cores halve the LDS return-bus bytes (3.2 GB total,
//   ~46 us floor at 69 TB/s; fp32 would be 85 us).
//   Per step per wave: 2x gll4 (512-B core slab) + 1x gll4 (256-B x row,
//   per-lane source addresses) -> WAITVM(4) -> 6 ds_read_b128 (cores) +
//   1 ds_read_b32 (x) -> dpp-broadcast m/x -> 48 v_fma_mix. 4 waves/SIMD.
//
// Cycle model: issue ~105 instr/wave-step -> ~770 cyc/SIMD-step; LDS bus
// ~100 KB/CU-step -> ~780 cyc. Both ~40-46 us -> kernel ~45-65 us.

#define NTHREADS 256

typedef _Float16 h2v __attribute__((ext_vector_type(2)));
typedef float f2 __attribute__((ext_vector_type(2)));

#define QBCAST(k) ((k) | ((k) << 2) | ((k) << 4) | ((k) << 6))

template <int CTRL>
__device__ __forceinline__ float dppf(float v) {
    return __builtin_bit_cast(float,
        __builtin_amdgcn_mov_dpp(__builtin_bit_cast(int, v), CTRL, 0xf, 0xf, false));
}

// async global->LDS, 4 B/lane: lane ln reads g(ln's addr), writes lds+ln*4
__device__ __forceinline__ void gll4(const void* g, const void* l) {
    __builtin_amdgcn_global_load_lds(
        (const __attribute__((address_space(1))) unsigned int*)g,
        (const __attribute__((address_space(3))) unsigned int*)l, 4, 0, 0);
}

#define WAITVM(N) asm volatile("s_waitcnt vmcnt(" #N ")" ::: "memory")
#define SBAR()    __builtin_amdgcn_sched_barrier(0)

// Pack cm[126,8,4,8] -> fp16-pair slabs of 128 dwords (512 B) per step:
// dword d = w*16 + i*4 + e (w<6, i<4, e<4) holds kj = w*4+e (k=kj/3,
// j=kj%3): halves (cm[c,k,j,i], cm[c,k,j,i+4]). d in [96,128) = pad.
// +128-dword zero tail.
__global__ __launch_bounds__(NTHREADS) void pack_cores_hq(
    const float* __restrict__ cm, unsigned int* __restrict__ cpk)
{
    int t = blockIdx.x * NTHREADS + threadIdx.x;
    if (t >= 126 * 128 + 128) return;
    if (t >= 126 * 128) { cpk[t] = 0u; return; }   // tail pad
    int c = t >> 7, d = t & 127;
    if (d >= 96) { cpk[t] = 0u; return; }          // slab pad
    int w = d >> 4, r = d & 15;
    int i = r >> 2, e = r & 3;
    int kj = w * 4 + e;            // 0..23
    int k = kj / 3, j = kj % 3;
    h2v h;
    h.x = (_Float16)cm[c * 256 + k * 32 + j * 8 + i];
    h.y = (_Float16)cm[c * 256 + k * 32 + j * 8 + i + 4];
    cpk[t] = __builtin_bit_cast(unsigned int, h);
}

#define KB16(MS, K) {                                                 \
    const float mk = dppf<QBCAST((K) & 3)>(MS);                       \
    const float p0 = mk * x0, p1 = mk * x1, p2 = mk * x2;             \
    { h2v h = __builtin_bit_cast(h2v, Sd[(K)*3 + 0]);                 \
      nm.x = fmaf((float)h.x, p0, nm.x);                              \
      nm.y = fmaf((float)h.y, p0, nm.y); }                            \
    { h2v h = __builtin_bit_cast(h2v, Sd[(K)*3 + 1]);                 \
      nm.x = fmaf((float)h.x, p1, nm.x);                              \
      nm.y = fmaf((float)h.y, p1, nm.y); }                            \
    { h2v h = __builtin_bit_cast(h2v, Sd[(K)*3 + 2]);                 \
      nm.x = fmaf((float)h.x, p2, nm.x);                              \
      nm.y = fmaf((float)h.y, p2, nm.y); } }

__global__ __launch_bounds__(NTHREADS, 4) void tt_chain_l(
    const float* __restrict__ x,            // [N,128,4]
    const unsigned int* __restrict__ cpk,   // packed fp16 slabs (+pad)
    const float* __restrict__ cf,           // [1,4,8]
    const float* __restrict__ cl,           // [8,4,2]
    float* __restrict__ out)                // [N,2]
{
    // per-wave private: core ring 2x512B + x ring 4x256B = 2 KB
    __shared__ __align__(16) unsigned int lds[4][512];

    const int tid = threadIdx.x;
    const int i   = tid & 3;                      // lane-in-quad
    const int ln  = tid & 63;                     // hw lane
    const int wv  = tid >> 6;                     // wave id
    const int n   = blockIdx.x * 64 + (tid >> 2); // sample

    unsigned int* CR = lds[wv];         // core ring: slot s at [s*128, +128)
    unsigned int* XR = lds[wv] + 256;   // x ring:   slot t at [t*64, +64)

    const char* cpkB = (const char*)cpk;
    const char* xS   = (const char*)x + (size_t)n * 2048 + i * 4;

    // ---- prologue staging: core slab 0, x rows 1..3 ----
    gll4(cpkB + (size_t)ln * 4,       CR);
    gll4(cpkB + 256 + (size_t)ln * 4, CR + 64);
    gll4(xS + 16, XR);          // row 1 -> slot 0
    gll4(xS + 32, XR + 64);     // row 2 -> slot 1
    gll4(xS + 48, XR + 128);    // row 3 -> slot 2

    // m init from row 0 (compiler-managed loads, prologue only)
    const float4 xr0 = *(const float4*)((const char*)x + (size_t)n * 2048);
    f2 m2;
    m2.x = fmaf(cf[i],      xr0.x, fmaf(cf[8 + i],  xr0.y,
           fmaf(cf[16 + i], xr0.z, cf[24 + i] * xr0.w)));
    m2.y = fmaf(cf[4 + i],  xr0.x, fmaf(cf[12 + i], xr0.y,
           fmaf(cf[20 + i], xr0.z, cf[28 + i] * xr0.w)));

    WAITVM(0);      // deterministic state: nothing outstanding
    SBAR();

    // invariant at step c: core slab c resident in CR slot (c&1); x row
    // c+1 resident in XR slot (c&3). Step c stages slab c+1 and row c+4.
    #pragma unroll 1
    for (int c = 0; c < 126; ++c) {
        const int cn = (c + 1 < 126) ? c + 1 : 125;      // clamp: pad stage
        const int rn = (c + 4 < 128) ? c + 4 : 127;      // never consumed
        const char* cs = cpkB + (size_t)cn * 512;
        gll4(cs + (size_t)ln * 4,       CR + ((c + 1) & 1) * 128);
        gll4(cs + 256 + (size_t)ln * 4, CR + ((c + 1) & 1) * 128 + 64);
        gll4(xS + (size_t)rn * 16,      XR + ((c + 3) & 3) * 64);
        WAITVM(4);   // survivors: this step's 3 + prev step's x = 4
        SBAR();

        const float xc = __builtin_bit_cast(float, XR[(c & 3) * 64 + ln]);
        const int4* Cb = (const int4*)(CR + (c & 1) * 128);
        unsigned int Sd[24];
        #pragma unroll
        for (int q = 0; q < 6; ++q) {
            int4 T = Cb[q * 4 + i];                      // ds_read_b128
            Sd[q*4+0] = T.x; Sd[q*4+1] = T.y; Sd[q*4+2] = T.z; Sd[q*4+3] = T.w;
        }

        const float x0 = dppf<QBCAST(0)>(xc);
        const float x1 = dppf<QBCAST(1)>(xc);
        const float x2 = dppf<QBCAST(2)>(xc);
        const float x3 = dppf<QBCAST(3)>(xc);
        f2 nm; nm.x = x3 * m2.x; nm.y = x3 * m2.y;      // j=3 identity, fp32
        KB16(m2.x, 0) KB16(m2.x, 1) KB16(m2.x, 2) KB16(m2.x, 3)
        KB16(m2.y, 4) KB16(m2.y, 5) KB16(m2.y, 6) KB16(m2.y, 7)
        m2 = nm;
    }

    WAITVM(0);
    SBAR();

    // ---- epilogue: x row 127 sits in XR slot 3 (staged at step 124) ----
    {
        const float xl = __builtin_bit_cast(float, XR[3 * 64 + ln]);
        const float e0 = dppf<QBCAST(0)>(xl);
        const float e1 = dppf<QBCAST(1)>(xl);
        const float e2 = dppf<QBCAST(2)>(xl);
        const float e3 = dppf<QBCAST(3)>(xl);
        const float xj[4] = { e0, e1, e2, e3 };
        float o0 = 0.f, o1 = 0.f;
        #pragma unroll
        for (int j = 0; j < 4; ++j) {
            o0 += xj[j] * (m2.x * cl[i * 8 + j * 2 + 0] +
                           m2.y * cl[(i + 4) * 8 + j * 2 + 0]);
            o1 += xj[j] * (m2.x * cl[i * 8 + j * 2 + 1] +
                           m2.y * cl[(i + 4) * 8 + j * 2 + 1]);
        }
        // quad reduction (sum over the 4 lanes of the sample)
        o0 += dppf<0xB1>(o0);   // quad_perm(1,0,3,2)
        o0 += dppf<0x4E>(o0);   // quad_perm(2,3,0,1)
        o1 += dppf<0xB1>(o1);
        o1 += dppf<0x4E>(o1);
        if (i == 0)
            reinterpret_cast<float2*>(out)[n] = make_float2(o0, o1);
    }
}

extern "C" void kernel_launch(void* const* d_in, const int* in_sizes, int n_in,
                              void* d_out, int out_size, void* d_ws, size_t ws_size,
                              hipStream_t stream) {
    const float* x  = (const float*)d_in[0];   // [N,128,4]
    const float* cf = (const float*)d_in[1];   // [1,4,8]
    const float* cm = (const float*)d_in[2];   // [126,8,4,8]
    const float* cl = (const float*)d_in[3];   // [8,4,2]
    float* out = (float*)d_out;                // [N,2]

    const int N = in_sizes[0] / (128 * 4);

    // packed fp16 slabs: (126*128 + 128) dwords = 65024 B in workspace
    unsigned int* cpk = (unsigned int*)d_ws;

    pack_cores_hq<<<(126 * 128 + 128 + NTHREADS - 1) / NTHREADS, NTHREADS, 0, stream>>>(cm, cpk);

    tt_chain_l<<<N / 64, NTHREADS, 0, stream>>>(x, cpk, cf, cl, out);
}